// Round 6
// baseline (131.654 us; speedup 1.0000x reference)
//
#include <hip/hip_runtime.h>

#define B_  4
#define QL  128
#define CL  512
#define XD  64
#define ED  128
#define DD  128
#define YD  32
#define MAGIC 0x5F3A9C71u

typedef __attribute__((ext_vector_type(8))) _Float16 f16x8;
typedef __attribute__((ext_vector_type(4))) float f32x4;

__device__ __forceinline__ float rdlane(float v, int l) {
  return __uint_as_float(__builtin_amdgcn_readlane(__float_as_uint(v), l));
}

// ws: fph f16 fragment-ordered [512 chunks][64 lanes][8 e] = 512 KB, then
//     flags u32 [512] = 2 KB (one per block; MAGIC = "my 4 fp rows are visible").
// fph chunk = ((b*4+t)*4+kk)*8 + wrow*4 + ct ; lane = lhi*16+llo ; elem = e
//   holds fp[b][t*128+wrow*64+ct*16+llo][kk*32+lhi*8+e]
__launch_bounds__(256, 2)
__global__ void fused_kernel(const float* __restrict__ qg,
                             const float* __restrict__ fg,
                             const float* __restrict__ lgg,
                             const float* __restrict__ W0,
                             const float* __restrict__ b0,
                             const float* __restrict__ W1,
                             const float* __restrict__ b1,
                             const float* __restrict__ Wo,
                             const float* __restrict__ bo,
                             _Float16* __restrict__ fph,
                             unsigned* __restrict__ flags,
                             float* __restrict__ out) {
  __shared__ float att[CL];
  __shared__ _Float16 qp16[DD];
  __shared__ float g[4][DD];
  __shared__ float red[8];
  __shared__ float part[8][YD];

  const int tid = threadIdx.x;
  const int bid = blockIdx.x;          // b*QL + qi
  const int wid = tid >> 6, ln = tid & 63;
  const int b = bid >> 7, qi = bid & 127;

  // ========== A. PRODUCE fp rows qi*4 .. qi*4+3 (unconditional, first) ==========
  {
    const int d = tid & 127, half = tid >> 7;
    const int c0 = qi * 4 + half * 2;
    const float* fr0 = fg + ((size_t)(b * CL + c0)) * ED;
    const float* fr1 = fr0 + ED;
    float fA0 = fr0[ln], fB0 = fr0[ln + 64];
    float fA1 = fr1[ln], fB1 = fr1[ln + 64];
    float a0 = 0.f, a1 = 0.f;
    const float* w = W0 + XD * DD + d;
    #pragma unroll
    for (int e = 0; e < 64; ++e) {
      float wv = w[e * DD];
      a0 = fmaf(rdlane(fA0, e), wv, a0);
      a1 = fmaf(rdlane(fA1, e), wv, a1);
    }
    #pragma unroll
    for (int e = 0; e < 64; ++e) {
      float wv = w[(64 + e) * DD];
      a0 = fmaf(rdlane(fB0, e), wv, a0);
      a1 = fmaf(rdlane(fB1, e), wv, a1);
    }
    const int kk = d >> 5, lhi2 = (d >> 3) & 3, e2 = d & 7;
    const int t = qi >> 5;
    #pragma unroll
    for (int r = 0; r < 2; ++r) {
      int c = c0 + r, cc = c & 127;
      int chunk = ((b * 4 + t) * 4 + kk) * 8 + (cc >> 6) * 4 + ((cc >> 4) & 3);
      fph[((size_t)chunk << 9) + ((size_t)(lhi2 * 16 + (cc & 15)) << 3) + e2] =
          (_Float16)(r == 0 ? a0 : a1);
    }
  }
  __threadfence();                 // make fp stores agent-visible
  __syncthreads();                 // all threads' stores+fences done
  if (tid == 0)
    __hip_atomic_store(&flags[bid], MAGIC, __ATOMIC_RELEASE, __HIP_MEMORY_SCOPE_AGENT);

  // ========== B. softmax over this row's 512 logits ==========
  {
    const float* lgr = lgg + (size_t)bid * CL;
    float l0 = lgr[tid], l1 = lgr[tid + 256];
    float m = fmaxf(l0, l1);
    #pragma unroll
    for (int off = 1; off < 64; off <<= 1) m = fmaxf(m, __shfl_xor(m, off, 64));
    if (ln == 0) red[wid] = m;
    __syncthreads();
    m = fmaxf(fmaxf(red[0], red[1]), fmaxf(red[2], red[3]));
    float p0 = expf(l0 - m), p1 = expf(l1 - m);
    float s = p0 + p1;
    #pragma unroll
    for (int off = 1; off < 64; off <<= 1) s += __shfl_xor(s, off, 64);
    if (ln == 0) red[4 + wid] = s;
    __syncthreads();
    float inv = 1.f / (red[4] + red[5] + red[6] + red[7]);
    att[tid] = p0 * inv;
    att[tid + 256] = p1 * inv;
  }

  // ========== C. qp[d] = b0[d] + sum_x q[x]*W0[x][d] (block-local) ==========
  if (tid < 128) {
    const float* qr = qg + (size_t)bid * XD;
    float qv = qr[ln];
    float acc = b0[tid];
    const float* w = W0 + tid;
    #pragma unroll
    for (int x = 0; x < XD; ++x)
      acc = fmaf(rdlane(qv, x), w[x * DD], acc);
    qp16[tid] = (_Float16)acc;
  }

  // ========== D. W1 B-fragments gathered straight from global (L2-hot) ==========
  const int wrow = wid >> 1, wcol = wid & 1;
  const int lhi = ln >> 4, llo = ln & 15;
  f16x8 wf[4][4];
  #pragma unroll
  for (int kk = 0; kk < 4; ++kk)
    #pragma unroll
    for (int jt = 0; jt < 4; ++jt)
      #pragma unroll
      for (int e = 0; e < 8; ++e)
        wf[kk][jt][e] = (_Float16)W1[(kk * 32 + lhi * 8 + e) * DD + wcol * 64 + jt * 16 + llo];

  __syncthreads();                 // att + qp16 visible to all waves

  f16x8 qpv[4];
  #pragma unroll
  for (int kk = 0; kk < 4; ++kk)
    qpv[kk] = *(const f16x8*)(qp16 + kk * 32 + lhi * 8);

  const int j0 = wcol * 64 + llo;
  float b1v[4];
  #pragma unroll
  for (int jt = 0; jt < 4; ++jt) b1v[jt] = b1[j0 + jt * 16];

  float gp[4] = {0.f, 0.f, 0.f, 0.f};
  const f16x8 zf = {};
  const uint4* fpv = (const uint4*)fph;

  // ========== E. 4 c-tiles: wait on producer group (b,t), then MFMA ==========
  for (int t = 0; t < 4; ++t) {
    if (wid == 0) {
      const unsigned* fl = flags + b * 128 + t * 32 + (ln & 31);
      while (true) {
        unsigned v = __hip_atomic_load(fl, __ATOMIC_RELAXED, __HIP_MEMORY_SCOPE_AGENT);
        if (__all(v == MAGIC)) break;
        __builtin_amdgcn_s_sleep(8);
      }
    }
    __syncthreads();
    {  // per-thread acquire for cross-XCD visibility of fph
      unsigned dv = __hip_atomic_load(flags + b * 128 + t * 32 + (tid & 31),
                                      __ATOMIC_ACQUIRE, __HIP_MEMORY_SCOPE_AGENT);
      asm volatile("" :: "v"(dv));
    }

    f32x4 acc[4][4];
    #pragma unroll
    for (int ct = 0; ct < 4; ++ct)
      #pragma unroll
      for (int jt = 0; jt < 4; ++jt)
        acc[ct][jt] = (f32x4){b1v[jt], b1v[jt], b1v[jt], b1v[jt]};   // b1 folded

    #pragma unroll
    for (int kk = 0; kk < 4; ++kk) {
      const int cb = ((((b * 4 + t) * 4 + kk) * 8 + wrow * 4) << 6);
      f16x8 a[4];
      #pragma unroll
      for (int ct = 0; ct < 4; ++ct) {
        uint4 u = fpv[cb + (ct << 6) + ln];                  // coalesced 1KB/wave
        f16x8 x = *(const f16x8*)&u + qpv[kk];               // v_pk_add_f16
        a[ct] = __builtin_elementwise_max(x, zf);            // relu
      }
      #pragma unroll
      for (int ct = 0; ct < 4; ++ct)
        #pragma unroll
        for (int jt = 0; jt < 4; ++jt)
          acc[ct][jt] = __builtin_amdgcn_mfma_f32_16x16x32_f16(a[ct], wf[kk][jt], acc[ct][jt], 0, 0, 0);
    }

    // epilogue: g[j] += att[c] * relu(H2)  (Wo GEMM commuted away; b1 in acc)
    const int cbase = t * 128 + wrow * 64 + lhi * 4;
    #pragma unroll
    for (int ct = 0; ct < 4; ++ct) {
      f32x4 a4 = *(const f32x4*)&att[cbase + ct * 16];
      #pragma unroll
      for (int r = 0; r < 4; ++r)
        #pragma unroll
        for (int jt = 0; jt < 4; ++jt)
          gp[jt] = fmaf(a4[r], fmaxf(acc[ct][jt][r], 0.f), gp[jt]);
    }
  }

  // ========== F. reduce + y = g @ Wo + bo ==========
  #pragma unroll
  for (int jt = 0; jt < 4; ++jt) {
    gp[jt] += __shfl_xor(gp[jt], 16, 64);
    gp[jt] += __shfl_xor(gp[jt], 32, 64);
  }
  ((float*)g)[tid] = 0.f;
  ((float*)g)[tid + 256] = 0.f;
  __syncthreads();
  if (ln < 16) {
    #pragma unroll
    for (int jt = 0; jt < 4; ++jt) g[wid][j0 + jt * 16] = gp[jt];
  }
  __syncthreads();

  {
    int y = tid & 31, ch = tid >> 5;
    float a = 0.f;
    #pragma unroll
    for (int jj = 0; jj < 16; ++jj) {
      int j = ch * 16 + jj;
      float gj = g[0][j] + g[1][j] + g[2][j] + g[3][j];
      a = fmaf(gj, Wo[j * YD + y], a);
    }
    part[ch][y] = a;
  }
  __syncthreads();
  if (tid < YD) {
    float a = bo[tid];
    #pragma unroll
    for (int ch = 0; ch < 8; ++ch) a += part[ch][tid];
    out[(size_t)bid * YD + tid] = a;
  }
}

extern "C" void kernel_launch(void* const* d_in, const int* in_sizes, int n_in,
                              void* d_out, int out_size, void* d_ws, size_t ws_size,
                              hipStream_t stream) {
  const float* q  = (const float*)d_in[0];
  const float* f  = (const float*)d_in[1];
  const float* lg = (const float*)d_in[2];
  const float* W0 = (const float*)d_in[3];
  const float* b0 = (const float*)d_in[4];
  const float* W1 = (const float*)d_in[5];
  const float* b1 = (const float*)d_in[6];
  const float* Wo = (const float*)d_in[7];
  const float* bo = (const float*)d_in[8];
  float* out = (float*)d_out;

  _Float16* fph = (_Float16*)d_ws;                          // 512 KB
  unsigned* flags = (unsigned*)((char*)d_ws + 512 * 1024);  //   2 KB

  fused_kernel<<<B_ * QL, 256, 0, stream>>>(q, f, lg, W0, b0, W1, b1, Wo, bo,
                                            fph, flags, out);
}

// Round 7
// 33.329 us; speedup vs baseline: 3.9501x; 3.9501x over previous
//
#include <hip/hip_runtime.h>

#define B_  4
#define QL  128
#define CL  512
#define XD  64
#define ED  128
#define DD  128
#define YD  32
#define MAGIC 0x5F3A9C71u

typedef __attribute__((ext_vector_type(8))) _Float16 f16x8;
typedef __attribute__((ext_vector_type(4))) float f32x4;
typedef unsigned long long u64;

__device__ __forceinline__ float rdlane(float v, int l) {
  return __uint_as_float(__builtin_amdgcn_readlane(__float_as_uint(v), l));
}

// ws: fph f16 fragment-ordered [512 chunks][64 lanes][8 e] = 512 KB (MALL-coherent,
//     accessed ONLY via agent-scope relaxed atomics), then flags u32 [512] = 2 KB.
// fph chunk = ((b*4+t)*4+kk)*8 + (cc>>6)*4 + ((cc>>4)&3); lane = lhi*16+(cc&15); elem e
//   holds fp[b][t*128 + cc][kk*32 + lhi*8 + e]   (cc = c & 127, t = c >> 7)
__launch_bounds__(256, 2)
__global__ void fused_kernel(const float* __restrict__ qg,
                             const float* __restrict__ fg,
                             const float* __restrict__ lgg,
                             const float* __restrict__ W0,
                             const float* __restrict__ b0,
                             const float* __restrict__ W1,
                             const float* __restrict__ b1,
                             const float* __restrict__ Wo,
                             const float* __restrict__ bo,
                             _Float16* __restrict__ fph,
                             unsigned* __restrict__ flags,
                             float* __restrict__ out) {
  __shared__ __align__(16) float att[CL];        //  2 KB
  __shared__ _Float16 qp16[DD];                  // 256 B
  __shared__ __align__(16) _Float16 wls[16384];  // 32 KB  W1 fragments
  __shared__ __align__(16) float fls[4][ED];     //  2 KB  staged f rows
  __shared__ float g[4][DD];                     //  2 KB
  __shared__ float red[8];
  __shared__ float part[8][YD];                  //  1 KB

  const int tid = threadIdx.x;
  const int bid = blockIdx.x;          // b*QL + qi
  const int wid = tid >> 6, ln = tid & 63;
  const int b = bid >> 7, qi = bid & 127;

  // ---- stage this block's 4 f rows (coalesced) ----
  {
    const float* src = fg + (size_t)(b * CL + qi * 4) * ED;
    ((float*)fls)[tid] = src[tid];
    ((float*)fls)[tid + 256] = src[tid + 256];
  }
  __syncthreads();

  // ===== A. PRODUCE 4 fp rows; one aligned 8B atomic store per thread =====
  if (tid < 128) {
    const int c = tid >> 5, r5 = tid & 31;
    const int kk = r5 >> 3, lhi = (r5 >> 1) & 3, eh = r5 & 1;
    const int d0 = kk * 32 + lhi * 8 + eh * 4;
    float a4[4] = {0.f, 0.f, 0.f, 0.f};
    const float* w = W0 + XD * DD + d0;
    const float* fr = fls[c];
    #pragma unroll 16
    for (int e = 0; e < ED; ++e) {
      f32x4 wv = *(const f32x4*)(w + e * DD);
      float fv = fr[e];
      #pragma unroll
      for (int j = 0; j < 4; ++j) a4[j] = fmaf(fv, wv[j], a4[j]);
    }
    union { u64 q; _Float16 h[4]; } pk;
    #pragma unroll
    for (int j = 0; j < 4; ++j) pk.h[j] = (_Float16)a4[j];
    const int t = qi >> 5;
    const int cc = (qi * 4 + c) & 127;
    const int chunk = ((b * 4 + t) * 4 + kk) * 8 + (cc >> 6) * 4 + ((cc >> 4) & 3);
    const size_t qidx = (size_t)chunk * 128 + (size_t)(lhi * 16 + (cc & 15)) * 2 + eh;
    __hip_atomic_store((u64*)fph + qidx, pk.q, __ATOMIC_RELAXED, __HIP_MEMORY_SCOPE_AGENT);
  }
  __syncthreads();                     // drains vmcnt: stores are at the coherent point
  if (tid == 0)
    __hip_atomic_store(&flags[bid], MAGIC, __ATOMIC_RELEASE, __HIP_MEMORY_SCOPE_AGENT);

  // ===== B. W1 fragments -> LDS (block-local, cached input loads) =====
  {
    #pragma unroll
    for (int i = 0; i < 8; ++i) {
      int F = i * 256 + tid;           // fragment id: ((wc*4+kk)*4+jt)*64 + lane
      int lane = F & 63, jt = (F >> 6) & 3, kk = (F >> 8) & 3, wc = (F >> 10) & 1;
      int col = wc * 64 + jt * 16 + (lane & 15);
      int krow = kk * 32 + (lane >> 4) * 8;
      f16x8 v;
      #pragma unroll
      for (int e = 0; e < 8; ++e) v[e] = (_Float16)W1[(krow + e) * DD + col];
      *(f16x8*)(wls + (size_t)F * 8) = v;
    }
  }

  // ===== C. softmax over this row's 512 logits =====
  {
    const float* lgr = lgg + (size_t)bid * CL;
    float l0 = lgr[tid], l1 = lgr[tid + 256];
    float m = fmaxf(l0, l1);
    #pragma unroll
    for (int off = 1; off < 64; off <<= 1) m = fmaxf(m, __shfl_xor(m, off, 64));
    if (ln == 0) red[wid] = m;
    __syncthreads();
    m = fmaxf(fmaxf(red[0], red[1]), fmaxf(red[2], red[3]));
    float p0 = expf(l0 - m), p1 = expf(l1 - m);
    float s = p0 + p1;
    #pragma unroll
    for (int off = 1; off < 64; off <<= 1) s += __shfl_xor(s, off, 64);
    if (ln == 0) red[4 + wid] = s;
    __syncthreads();
    float inv = 1.f / (red[4] + red[5] + red[6] + red[7]);
    att[tid] = p0 * inv;
    att[tid + 256] = p1 * inv;
  }

  // ===== D. qp[d] = b0[d] + sum_x q[x]*W0[x][d] (block-local) =====
  if (tid < 128) {
    const float* qr = qg + (size_t)bid * XD;
    float qv = qr[ln];
    float acc = b0[tid];
    const float* w = W0 + tid;
    #pragma unroll
    for (int x = 0; x < XD; ++x)
      acc = fmaf(rdlane(qv, x), w[x * DD], acc);
    qp16[tid] = (_Float16)acc;
  }
  __syncthreads();                     // att, qp16, wls all visible

  // ===== E. GEMM: 4 c-tiles with per-tile producer-group wait =====
  const int wrow = wid >> 1, wcol = wid & 1;
  const int lhi = ln >> 4, llo = ln & 15;

  f16x8 qpv[4];
  #pragma unroll
  for (int kk = 0; kk < 4; ++kk)
    qpv[kk] = *(const f16x8*)(qp16 + kk * 32 + lhi * 8);

  const int j0 = wcol * 64 + llo;
  float b1v[4];
  #pragma unroll
  for (int jt = 0; jt < 4; ++jt) b1v[jt] = b1[j0 + jt * 16];

  float gp[4] = {0.f, 0.f, 0.f, 0.f};
  const f16x8 zf = {};
  const u64* fpq = (const u64*)fph;

  for (int t = 0; t < 4; ++t) {
    if (wid == 0) {
      const unsigned* fl = flags + b * 128 + t * 32 + (ln & 31);
      while (true) {
        unsigned v = __hip_atomic_load(fl, __ATOMIC_RELAXED, __HIP_MEMORY_SCOPE_AGENT);
        if (__all(v == MAGIC)) break;
        __builtin_amdgcn_s_sleep(2);
      }
    }
    __syncthreads();

    f32x4 acc[4][4];
    #pragma unroll
    for (int ct = 0; ct < 4; ++ct)
      #pragma unroll
      for (int jt = 0; jt < 4; ++jt)
        acc[ct][jt] = (f32x4){b1v[jt], b1v[jt], b1v[jt], b1v[jt]};   // b1 folded

    #pragma unroll
    for (int kk = 0; kk < 4; ++kk) {
      const int chunk0 = ((b * 4 + t) * 4 + kk) * 8 + wrow * 4;
      f16x8 a[4];
      #pragma unroll
      for (int ct = 0; ct < 4; ++ct) {
        union { u64 q[2]; f16x8 v; } u;
        const size_t base = (size_t)(chunk0 + ct) * 128 + (size_t)ln * 2;
        u.q[0] = __hip_atomic_load(fpq + base,     __ATOMIC_RELAXED, __HIP_MEMORY_SCOPE_AGENT);
        u.q[1] = __hip_atomic_load(fpq + base + 1, __ATOMIC_RELAXED, __HIP_MEMORY_SCOPE_AGENT);
        f16x8 x = u.v + qpv[kk];                       // v_pk_add_f16
        a[ct] = __builtin_elementwise_max(x, zf);      // relu
      }
      f16x8 wfk[4];
      #pragma unroll
      for (int jt = 0; jt < 4; ++jt)
        wfk[jt] = *(const f16x8*)(wls + (size_t)((((wcol * 4 + kk) * 4 + jt) * 64 + ln) * 8));
      #pragma unroll
      for (int ct = 0; ct < 4; ++ct)
        #pragma unroll
        for (int jt = 0; jt < 4; ++jt)
          acc[ct][jt] = __builtin_amdgcn_mfma_f32_16x16x32_f16(a[ct], wfk[jt], acc[ct][jt], 0, 0, 0);
    }

    // epilogue: g[j] += att[c] * relu(H2)   (Wo GEMM commuted away; b1 in acc)
    const int cbase = t * 128 + wrow * 64 + lhi * 4;
    #pragma unroll
    for (int ct = 0; ct < 4; ++ct) {
      f32x4 a4 = *(const f32x4*)&att[cbase + ct * 16];
      #pragma unroll
      for (int r = 0; r < 4; ++r)
        #pragma unroll
        for (int jt = 0; jt < 4; ++jt)
          gp[jt] = fmaf(a4[r], fmaxf(acc[ct][jt][r], 0.f), gp[jt]);
    }
  }

  // ===== F. reduce + y = g @ Wo + bo =====
  #pragma unroll
  for (int jt = 0; jt < 4; ++jt) {
    gp[jt] += __shfl_xor(gp[jt], 16, 64);
    gp[jt] += __shfl_xor(gp[jt], 32, 64);
  }
  ((float*)g)[tid] = 0.f;
  ((float*)g)[tid + 256] = 0.f;
  __syncthreads();
  if (ln < 16) {
    #pragma unroll
    for (int jt = 0; jt < 4; ++jt) g[wid][j0 + jt * 16] = gp[jt];
  }
  __syncthreads();

  {
    int y = tid & 31, ch = tid >> 5;
    float a = 0.f;
    #pragma unroll
    for (int jj = 0; jj < 16; ++jj) {
      int j = ch * 16 + jj;
      float gj = g[0][j] + g[1][j] + g[2][j] + g[3][j];
      a = fmaf(gj, Wo[j * YD + y], a);
    }
    part[ch][y] = a;
  }
  __syncthreads();
  if (tid < YD) {
    float a = bo[tid];
    #pragma unroll
    for (int ch = 0; ch < 8; ++ch) a += part[ch][tid];
    out[(size_t)bid * YD + tid] = a;
  }
}

extern "C" void kernel_launch(void* const* d_in, const int* in_sizes, int n_in,
                              void* d_out, int out_size, void* d_ws, size_t ws_size,
                              hipStream_t stream) {
  const float* q  = (const float*)d_in[0];
  const float* f  = (const float*)d_in[1];
  const float* lg = (const float*)d_in[2];
  const float* W0 = (const float*)d_in[3];
  const float* b0 = (const float*)d_in[4];
  const float* W1 = (const float*)d_in[5];
  const float* b1 = (const float*)d_in[6];
  const float* Wo = (const float*)d_in[7];
  const float* bo = (const float*)d_in[8];
  float* out = (float*)d_out;

  _Float16* fph = (_Float16*)d_ws;                          // 512 KB
  unsigned* flags = (unsigned*)((char*)d_ws + 512 * 1024);  //   2 KB

  fused_kernel<<<B_ * QL, 256, 0, stream>>>(q, f, lg, W0, b0, W1, b1, Wo, bo,
                                            fph, flags, out);
}

// Round 10
// 26.089 us; speedup vs baseline: 5.0463x; 1.2775x over previous
//
#include <hip/hip_runtime.h>

#define B_  4
#define QL  128
#define CL  512
#define XD  64
#define ED  128
#define DD  128
#define YD  32
#define MAGIC 0x5F3A9C71u

typedef __attribute__((ext_vector_type(8))) _Float16 f16x8;
typedef __attribute__((ext_vector_type(4))) float f32x4;
typedef unsigned long long u64;

__device__ __forceinline__ float rdlane(float v, int l) {
  return __uint_as_float(__builtin_amdgcn_readlane(__float_as_uint(v), l));
}

// ws: fph f16 fragment-ordered, 512 KB; flags u32 [256], 1 KB.
// fph u64-index = chunk*128 + (lhi*16 + llo)*2 + eh, chunk = ((b*4+t)*4+kk)*8 + wr
//   holds fp[b][t*128 + wr*16 + llo][kk*32 + lhi*8 + eh*4 .. +3]
// fph/flags traffic: agent-scope RELAXED atomics only (write-through to MALL,
// no cache invalidates/writebacks) + one RELEASE flag store -- R7-proven protocol.
__launch_bounds__(512, 2)
__global__ void fused_kernel(const float* __restrict__ qg,
                             const float* __restrict__ fg,
                             const float* __restrict__ lgg,
                             const float* __restrict__ W0,
                             const float* __restrict__ b0,
                             const float* __restrict__ W1,
                             const float* __restrict__ b1,
                             const float* __restrict__ Wo,
                             const float* __restrict__ bo,
                             _Float16* __restrict__ fph,
                             unsigned* __restrict__ flags,
                             float* __restrict__ out) {
  __shared__ __align__(16) float att[2][CL];     //  4 KB
  __shared__ __align__(16) _Float16 qp16[2][DD]; // 512 B
  __shared__ __align__(16) _Float16 wls[16384];  // 32 KB  W1 B-frags [kk][jt8][lane][8]
  __shared__ __align__(16) float fls[8][ED];     //  4 KB  staged f rows
  __shared__ float g[2][8][DD];                  //  8 KB
  __shared__ float red[16];
  __shared__ float part[2][8][YD];               //  2 KB

  const int tid = threadIdx.x;
  const int bid = blockIdx.x;            // b*64 + qpair
  const int wid = tid >> 6, ln = tid & 63;
  const int b = bid >> 6, qpair = bid & 63;

  // ---- stage this block's 8 producer f rows (coalesced) ----
  {
    const float* src = fg + ((size_t)(b * CL + qpair * 8)) * ED;
    ((float*)fls)[tid] = src[tid];
    ((float*)fls)[tid + 512] = src[tid + 512];
  }
  __syncthreads();

  // ===== A. PRODUCE 8 fp rows (32 thr/row, u64 store of 4 d) =====
  if (tid < 256) {
    const int c_local = tid >> 5;        // 0..7
    const int r5 = tid & 31;
    const int kk = r5 >> 3, lhi = (r5 >> 1) & 3, eh = r5 & 1;
    const int d0 = kk * 32 + lhi * 8 + eh * 4;   // = 4*r5, coalesced
    float a4[4] = {0.f, 0.f, 0.f, 0.f};
    const float* w = W0 + XD * DD + d0;
    const float* fr = fls[c_local];
    #pragma unroll 16
    for (int e = 0; e < ED; ++e) {
      f32x4 wv = *(const f32x4*)(w + e * DD);
      float fv = fr[e];
      #pragma unroll
      for (int j = 0; j < 4; ++j) a4[j] = fmaf(fv, wv[j], a4[j]);
    }
    union { u64 q; _Float16 h[4]; } pk;
    #pragma unroll
    for (int j = 0; j < 4; ++j) pk.h[j] = (_Float16)a4[j];
    const int c = qpair * 8 + c_local;   // 0..511 within batch b
    const int cc = c & 127, t = c >> 7;
    const int chunk = ((b * 4 + t) * 4 + kk) * 8 + (cc >> 4);
    const size_t qidx = (size_t)chunk * 128 + (size_t)(lhi * 16 + (cc & 15)) * 2 + eh;
    __hip_atomic_store((u64*)fph + qidx, pk.q, __ATOMIC_RELAXED, __HIP_MEMORY_SCOPE_AGENT);
  }
  __syncthreads();                       // compiler emits vmcnt(0) before s_barrier:
                                         // all write-through stores are at the MALL
  if (tid == 0)
    __hip_atomic_store(&flags[bid], MAGIC, __ATOMIC_RELEASE, __HIP_MEMORY_SCOPE_AGENT);

  // ===== B. W1 B-fragments -> LDS (2048 frags: 512 thr x 4 iters) =====
  #pragma unroll
  for (int i = 0; i < 4; ++i) {          // BUGFIX R8/R9: was i<2 (half of wls uninit)
    int F = i * 512 + tid;               // frag id: (kk*8+jt)*64 + lane, 0..2047
    int lane = F & 63, jt = (F >> 6) & 7, kk = F >> 9;
    int col = jt * 16 + (lane & 15);
    int krow = kk * 32 + (lane >> 4) * 8;
    f16x8 v;
    #pragma unroll
    for (int e = 0; e < 8; ++e) v[e] = (_Float16)W1[(krow + e) * DD + col];
    *(f16x8*)(wls + (size_t)F * 8) = v;
  }

  // ===== C. softmax for the block's 2 q rows =====
  {
    const int q_ = tid >> 8, i = tid & 255;     // waves 0-3 -> q0, 4-7 -> q1
    const float* lgr = lgg + ((size_t)(b * QL + qpair * 2 + q_)) * CL;
    float l0 = lgr[i], l1 = lgr[i + 256];
    float m = fmaxf(l0, l1);
    #pragma unroll
    for (int off = 1; off < 64; off <<= 1) m = fmaxf(m, __shfl_xor(m, off, 64));
    if (ln == 0) red[wid] = m;
    __syncthreads();
    m = fmaxf(fmaxf(red[q_ * 4], red[q_ * 4 + 1]), fmaxf(red[q_ * 4 + 2], red[q_ * 4 + 3]));
    float p0 = expf(l0 - m), p1 = expf(l1 - m);
    float s = p0 + p1;
    #pragma unroll
    for (int off = 1; off < 64; off <<= 1) s += __shfl_xor(s, off, 64);
    if (ln == 0) red[8 + wid] = s;
    __syncthreads();
    float inv = 1.f / (red[8 + q_ * 4] + red[9 + q_ * 4] + red[10 + q_ * 4] + red[11 + q_ * 4]);
    att[q_][i] = p0 * inv;
    att[q_][i + 256] = p1 * inv;
  }

  // ===== D. qp for the 2 q rows (threads 0..255) =====
  if (tid < 256) {
    const int q_ = tid >> 7, d = tid & 127;
    const float* qr = qg + ((size_t)(b * QL + qpair * 2 + q_)) * XD;
    float qv = qr[ln];
    float acc = b0[d];
    const float* w = W0 + d;
    #pragma unroll
    for (int x = 0; x < XD; ++x)
      acc = fmaf(rdlane(qv, x), w[x * DD], acc);
    qp16[q_][d] = (_Float16)acc;
  }
  __syncthreads();                        // att, qp16, wls visible

  // ===== E. GEMM: wave wid owns c-slice wid*16, all 128 j, both q =====
  const int wr = wid;
  const int lhi = ln >> 4, llo = ln & 15;

  f16x8 qpv[2][4];
  #pragma unroll
  for (int q_ = 0; q_ < 2; ++q_)
    #pragma unroll
    for (int kk = 0; kk < 4; ++kk)
      qpv[q_][kk] = *(const f16x8*)(&qp16[q_][kk * 32 + lhi * 8]);

  float b1v[8];
  #pragma unroll
  for (int jt = 0; jt < 8; ++jt) b1v[jt] = b1[jt * 16 + llo];

  float gp[2][8];
  #pragma unroll
  for (int q_ = 0; q_ < 2; ++q_)
    #pragma unroll
    for (int jt = 0; jt < 8; ++jt) gp[q_][jt] = 0.f;

  const f16x8 zf = {};
  const u64* fpq = (const u64*)fph;

  for (int t = 0; t < 4; ++t) {
    // wait for the 16 producer blocks of (b, t)
    if (wid == 0) {
      const unsigned* fl = flags + b * 64 + t * 16 + (ln & 15);
      while (true) {
        unsigned v = __hip_atomic_load(fl, __ATOMIC_RELAXED, __HIP_MEMORY_SCOPE_AGENT);
        if (__all(v == MAGIC)) break;
        __builtin_amdgcn_s_sleep(2);
      }
    }
    __syncthreads();
    // compiler-only fence: forbid hoisting the fph loads above the wait.
    // (No ISA cache ops -- fph loads bypass caches anyway; R6 showed acquire
    //  invalidates are a 4x regression.)
    asm volatile("" ::: "memory");
    __builtin_amdgcn_sched_barrier(0);

    // A-fragments for this wave's 16 c-rows, reused for both q
    f16x8 araw[4];
    #pragma unroll
    for (int kk = 0; kk < 4; ++kk) {
      const int chunk = ((b * 4 + t) * 4 + kk) * 8 + wr;
      union { u64 q[2]; f16x8 v; } u;
      const size_t base = (size_t)chunk * 128 + (size_t)ln * 2;
      u.q[0] = __hip_atomic_load(fpq + base,     __ATOMIC_RELAXED, __HIP_MEMORY_SCOPE_AGENT);
      u.q[1] = __hip_atomic_load(fpq + base + 1, __ATOMIC_RELAXED, __HIP_MEMORY_SCOPE_AGENT);
      araw[kk] = u.v;
    }

    f32x4 acc[2][8];
    #pragma unroll
    for (int q_ = 0; q_ < 2; ++q_)
      #pragma unroll
      for (int jt = 0; jt < 8; ++jt)
        acc[q_][jt] = (f32x4){b1v[jt], b1v[jt], b1v[jt], b1v[jt]};   // b1 folded

    #pragma unroll
    for (int kk = 0; kk < 4; ++kk) {
      f16x8 a0 = __builtin_elementwise_max(araw[kk] + qpv[0][kk], zf);
      f16x8 a1 = __builtin_elementwise_max(araw[kk] + qpv[1][kk], zf);
      #pragma unroll
      for (int jt = 0; jt < 8; ++jt) {
        f16x8 wfv = *(const f16x8*)(wls + (size_t)((kk * 8 + jt) * 64 + ln) * 8);
        acc[0][jt] = __builtin_amdgcn_mfma_f32_16x16x32_f16(a0, wfv, acc[0][jt], 0, 0, 0);
        acc[1][jt] = __builtin_amdgcn_mfma_f32_16x16x32_f16(a1, wfv, acc[1][jt], 0, 0, 0);
      }
    }

    // epilogue: gp[q][jt] += att[q][c] * relu(H2)   (Wo GEMM commuted away)
    const int cb = t * 128 + wr * 16 + lhi * 4;
    #pragma unroll
    for (int q_ = 0; q_ < 2; ++q_) {
      f32x4 a4 = *(const f32x4*)&att[q_][cb];
      #pragma unroll
      for (int r = 0; r < 4; ++r)
        #pragma unroll
        for (int jt = 0; jt < 8; ++jt)
          gp[q_][jt] = fmaf(a4[r], fmaxf(acc[q_][jt][r], 0.f), gp[q_][jt]);
    }
  }

  // ===== F. reduce + y = g @ Wo + bo =====
  #pragma unroll
  for (int q_ = 0; q_ < 2; ++q_)
    #pragma unroll
    for (int jt = 0; jt < 8; ++jt) {
      gp[q_][jt] += __shfl_xor(gp[q_][jt], 16, 64);
      gp[q_][jt] += __shfl_xor(gp[q_][jt], 32, 64);
    }
  if (ln < 16) {
    #pragma unroll
    for (int q_ = 0; q_ < 2; ++q_)
      #pragma unroll
      for (int jt = 0; jt < 8; ++jt) g[q_][wid][jt * 16 + ln] = gp[q_][jt];
  }
  __syncthreads();

  {
    const int q_ = tid >> 8, rem = tid & 255;
    const int ch = rem >> 5, y = rem & 31;
    float a = 0.f;
    #pragma unroll
    for (int jj = 0; jj < 16; ++jj) {
      int j = ch * 16 + jj;
      float gj = g[q_][0][j] + g[q_][1][j] + g[q_][2][j] + g[q_][3][j]
               + g[q_][4][j] + g[q_][5][j] + g[q_][6][j] + g[q_][7][j];
      a = fmaf(gj, Wo[j * YD + y], a);
    }
    part[q_][ch][y] = a;
  }
  __syncthreads();
  if (tid < 64) {
    const int q_ = tid >> 5, y = tid & 31;
    float a = bo[y];
    #pragma unroll
    for (int ch = 0; ch < 8; ++ch) a += part[q_][ch][y];
    out[((size_t)(b * QL + qpair * 2 + q_)) * YD + y] = a;
  }
}

extern "C" void kernel_launch(void* const* d_in, const int* in_sizes, int n_in,
                              void* d_out, int out_size, void* d_ws, size_t ws_size,
                              hipStream_t stream) {
  const float* q  = (const float*)d_in[0];
  const float* f  = (const float*)d_in[1];
  const float* lg = (const float*)d_in[2];
  const float* W0 = (const float*)d_in[3];
  const float* b0 = (const float*)d_in[4];
  const float* W1 = (const float*)d_in[5];
  const float* b1 = (const float*)d_in[6];
  const float* Wo = (const float*)d_in[7];
  const float* bo = (const float*)d_in[8];
  float* out = (float*)d_out;

  _Float16* fph = (_Float16*)d_ws;                          // 512 KB
  unsigned* flags = (unsigned*)((char*)d_ws + 512 * 1024);  //   1 KB

  fused_kernel<<<256, 512, 0, stream>>>(q, f, lg, W0, b0, W1, b1, Wo, bo,
                                        fph, flags, out);
}